// Round 5
// baseline (426.886 us; speedup 1.0000x reference)
//
#include <hip/hip_runtime.h>

// B=8, T=20, C=1, H=512, W=512
#define FRAMES 160
#define HH 512
#define WW 512
#define STRIPS 16
#define NBLKW (2 * STRIPS * FRAMES)  // 5120 partial-sum slots
#define NTOT 41943040

// ---------------------------------------------------------------------------
// R4: back to the measured-best R0 structure (LDS prefix exchange, 16B/lane
// coalesced loads, VGPR~64, FETCH~unique) after R1-R3 showed the shuffle/
// 8-col rewrite loses more to register pressure + L1 reuse than it gains
// from dropping barriers. Two surgical changes vs R0:
//  1) barrier scope: one 128-thread parity group per block (grid 32x160)
//     so each s_barrier syncs only the 2 waves that actually share LDS;
//     2x blocks + VGPR 64 -> up to 8 waves/EU to hide LDS/barrier latency.
//  2) array fusion: SSIM needs only Sxx+Syy, so 5 prefix arrays -> 4
//     (X, Y, S=xx+yy, P=xy): -20% LDS traffic and prefix VALU.
// Load pattern / prefetch-across-lgkm-barrier / L_rec logic identical to R0.
// ---------------------------------------------------------------------------

// LDS-only barrier: waits lgkmcnt(0) but NOT vmcnt -> prefetched global
// loads stay in flight across barriers. 0xC07F = vmcnt63 expcnt7 lgkmcnt0.
__device__ __forceinline__ void sync_lds() {
  __builtin_amdgcn_s_waitcnt(0xC07F);
  __builtin_amdgcn_s_barrier();
}

// SSIM on raw [0,1) values (scale-invariant: C1,C2 divided by 255^2),
// numerator/denominator premultiplied by NP^2 (NP=49). sss = Wxx+Wyy.
__device__ __forceinline__ float ssim_fast(float a, float b, float sss,
                                           float sxy) {
  const float K1 = 0.2401f;        // 2401 * 1e-4
  const float K2 = 2.1609f;        // 2401 * 9e-4
  const float cA = 49.0f / 24.0f;
  const float cB = 49.0f / 48.0f;
  float ab = a * b;
  float s2 = fmaf(a, a, b * b);
  float A1 = fmaf(2.0f, ab, K1);
  float B1 = s2 + K1;
  float A2 = fmaf(cA, fmaf(49.0f, sxy, -ab), K2);
  float B2 = fmaf(cB, fmaf(49.0f, sss, -s2), K2);
  return (A1 * A2) * __builtin_amdgcn_rcpf(B1 * B2);
}

// prefix within the thread's 4 columns, store (P0,P1) / (P2,P3) to LDS
#define HSTORE(S, P, A)                          \
  P.x = S.x; P.y = P.x + S.y;                    \
  P.z = P.y + S.z; P.w = P.z + S.w;              \
  lds[A][0][q] = make_float2(P.x, P.y);          \
  lds[A][1][q] = make_float2(P.z, P.w);

// 7-wide windows at cols 4q..4q+3 from own prefixes + neighbor prefixes
#define HWIN(P, W, A) {                          \
  float2 h1 = lds[A][1][q + 1];                  \
  float2 l2 = lds[A][0][q + 2];                  \
  W.x = P.w + h1.x;                              \
  W.y = (P.w - P.x) + h1.y;                      \
  W.z = (P.w - P.y) + (h1.y + l2.x);             \
  W.w = (P.w - P.z) + (h1.y + l2.y); }

#define LREC(xv, yv) {                                         \
  float4 d_ = make_float4(xv.x - yv.x, xv.y - yv.y,            \
                          xv.z - yv.z, xv.w - yv.w);           \
  sabs += fabsf(d_.x) + fabsf(d_.y) + fabsf(d_.z) + fabsf(d_.w); \
  ssq += d_.x * d_.x + d_.y * d_.y;                            \
  ssq += d_.z * d_.z + d_.w * d_.w; }

#define VADD(xv, yv)                                    \
  Sx += xv; Sy += yv;                                   \
  Ss += xv * xv + yv * yv; Sp += xv * yv;

#define VSUB(xv, yv)                                    \
  Sx -= xv; Sy -= yv;                                   \
  Ss -= xv * xv + yv * yv; Sp -= xv * yv;

// grid (2*STRIPS, FRAMES), block 128 = one parity group (2 waves).
// strip = bx>>1, grp = bx&1. Group 0: even relative output rows; group 1:
// odd rows. Thread q owns cols 4q..4q+3. Strip s covers output rows
// [32s, 32s+n_out), n_out = 32 (s<15) or 26 (s=15); L_rec: grp0 counts
// rel rows 0..6 at init and <=30 on first slide-touch, grp1 counts rel 31.
__global__ __launch_bounds__(128, 4) void fused_kernel(
    const float* __restrict__ gsrc, const float* __restrict__ tsrc,
    float* __restrict__ ws) {
  const int strip = blockIdx.x >> 1;
  const int grp = blockIdx.x & 1;
  const int frame = blockIdx.y;
  const int row0 = strip * 32;
  const int n_iter = (strip == STRIPS - 1) ? 13 : 16;  // output-row pairs
  const int tid = threadIdx.x;
  const int q = tid;  // 0..127

  const float* gp = gsrc + ((size_t)frame * HH + row0 + grp) * WW + q * 4;
  const float* tp = tsrc + ((size_t)frame * HH + row0 + grp) * WW + q * 4;

  __shared__ float2 lds[4][2][132];  // [array][lo/hi][q(+pad)]

  float4 Sx = make_float4(0.f, 0.f, 0.f, 0.f);
  float4 Sy = Sx, Ss = Sx, Sp = Sx;
  float sabs = 0.f, ssq = 0.f, ssum = 0.f;

  // init window: rel rows grp..grp+6 (grp0's rows 0..6 are all owned)
  for (int i = 0; i < 7; ++i) {
    float4 xv = *(const float4*)(gp + i * WW);
    float4 yv = *(const float4*)(tp + i * WW);
    VADD(xv, yv)
    if (grp == 0) { LREC(xv, yv) }
  }

  for (int it = 0; it < n_iter; ++it) {
    const bool slide = (it + 1 < n_iter);
    // ---- prefetch the slide rows NOW; consume after the barriers ----
    float4 nx0, ny0, nx1, ny1, ox0, oy0, ox1, oy1;
    if (slide) {
      const float* pn = gp + (size_t)(2 * it + 7) * WW;
      const float* qn = tp + (size_t)(2 * it + 7) * WW;
      const float* po = gp + (size_t)(2 * it) * WW;
      const float* qo = tp + (size_t)(2 * it) * WW;
      nx0 = *(const float4*)pn;
      ny0 = *(const float4*)qn;
      nx1 = *(const float4*)(pn + WW);
      ny1 = *(const float4*)(qn + WW);
      ox0 = *(const float4*)po;
      oy0 = *(const float4*)qo;
      ox1 = *(const float4*)(po + WW);
      oy1 = *(const float4*)(qo + WW);
    }

    float4 Px, Py, Ps, Pp;
    HSTORE(Sx, Px, 0) HSTORE(Sy, Py, 1) HSTORE(Ss, Ps, 2) HSTORE(Sp, Pp, 3)
    sync_lds();  // lgkm-only: prefetched vm loads stay in flight
    float4 Wx, Wy, Wss, Wxy;
    HWIN(Px, Wx, 0) HWIN(Py, Wy, 1) HWIN(Ps, Wss, 2) HWIN(Pp, Wxy, 3)
    float v0 = ssim_fast(Wx.x, Wy.x, Wss.x, Wxy.x);
    float v1 = ssim_fast(Wx.y, Wy.y, Wss.y, Wxy.y);
    float v2 = ssim_fast(Wx.z, Wy.z, Wss.z, Wxy.z);
    float v3 = ssim_fast(Wx.w, Wy.w, Wss.w, Wxy.w);
    // valid output cols: 4q+j <= 505 (506 outputs); select-then-add is
    // NaN-safe against garbage in the LDS pad region.
    ssum += (q <= 126) ? v0 : 0.f;
    ssum += (q <= 126) ? v1 : 0.f;
    ssum += (q <= 125) ? v2 : 0.f;
    ssum += (q <= 125) ? v3 : 0.f;
    sync_lds();  // protect LDS for next iteration's writes

    if (slide) {
      // consume prefetched rows: add rel (2it+7,2it+8)+grp, retire
      // (2it,2it+1)+grp. Retired rows re-read from global: exact same
      // values as when added -> exact cancellation.
      VADD(nx0, ny0)
      VSUB(ox0, oy0)
      if ((grp == 0) && (2 * it + 7 <= 30)) { LREC(nx0, ny0) }
      VADD(nx1, ny1)
      VSUB(ox1, oy1)
      bool cnt = (grp == 0) ? (2 * it + 8 <= 30) : (2 * it + 9 == 31);
      if (cnt) { LREC(nx1, ny1) }
    }
  }

  // block reduce sabs / ssq / ssum (2 waves)
  #pragma unroll
  for (int off = 32; off > 0; off >>= 1) {
    sabs += __shfl_down(sabs, off, 64);
    ssq += __shfl_down(ssq, off, 64);
    ssum += __shfl_down(ssum, off, 64);
  }
  __syncthreads();  // full barrier before reusing lds as scratch
  float* scr = (float*)&lds[0][0][0];
  const int lane = tid & 63, wv = tid >> 6;
  if (lane == 0) { scr[wv] = sabs; scr[2 + wv] = ssq; scr[4 + wv] = ssum; }
  __syncthreads();
  if (tid == 0) {
    const int bid = blockIdx.y * (2 * STRIPS) + blockIdx.x;
    ws[bid] = scr[0] + scr[1];
    ws[NBLKW + bid] = scr[2] + scr[3];
    ws[2 * NBLKW + bid] = scr[4] + scr[5];
  }
}

__global__ __launch_bounds__(256) void finalize_kernel(
    const float* __restrict__ ws, const float* __restrict__ genD,
    float* __restrict__ out) {
  const int tid = threadIdx.x;
  float a = 0.f, b = 0.f, c = 0.f;
  for (int i = tid; i < NBLKW; i += 256) {
    a += ws[i];
    b += ws[NBLKW + i];
    c += ws[2 * NBLKW + i];
  }
  #pragma unroll
  for (int off = 32; off > 0; off >>= 1) {
    a += __shfl_down(a, off, 64);
    b += __shfl_down(b, off, 64);
    c += __shfl_down(c, off, 64);
  }
  __shared__ float la[4], lb[4], lc[4];
  const int lane = tid & 63, wv = tid >> 6;
  if (lane == 0) { la[wv] = a; lb[wv] = b; lc[wv] = c; }
  __syncthreads();
  if (tid == 0) {
    a = la[0] + la[1] + la[2] + la[3];
    b = lb[0] + lb[1] + lb[2] + lb[3];
    c = lc[0] + lc[1] + lc[2] + lc[3];
    const float invN = 1.0f / (float)NTOT;
    float L_rec = a * invN + b * invN;
    float L_ssim = c / (160.0f * 506.0f * 506.0f);
    float d = 0.f;
    #pragma unroll
    for (int i = 0; i < 8; ++i) d += genD[i];
    float L_adv = -d / 8.0f;
    float L_total = L_rec + 0.01f * (1.0f - L_ssim) + 0.0001f * L_adv;
    out[0] = L_total;
    out[1] = L_rec;
    out[2] = L_ssim;
    out[3] = L_adv;
  }
}

extern "C" void kernel_launch(void* const* d_in, const int* in_sizes, int n_in,
                              void* d_out, int out_size, void* d_ws,
                              size_t ws_size, hipStream_t stream) {
  const float* gen_img = (const float*)d_in[0];
  const float* target = (const float*)d_in[1];
  const float* gen_D = (const float*)d_in[2];
  float* out = (float*)d_out;
  float* ws = (float*)d_ws;

  dim3 grid(2 * STRIPS, FRAMES);
  fused_kernel<<<grid, 128, 0, stream>>>(gen_img, target, ws);
  finalize_kernel<<<1, 256, 0, stream>>>(ws, gen_D, out);
}

// Round 6
// 360.568 us; speedup vs baseline: 1.1839x; 1.1839x over previous
//
#include <hip/hip_runtime.h>

// B=8, T=20, C=1, H=512, W=512
#define FRAMES 160
#define HH 512
#define WW 512
#define STRIPS 16
#define NBLK (STRIPS * FRAMES)   // 2560
#define NTOT 41943040

// ---------------------------------------------------------------------------
// R5: R0 structure (measured best: 141us, FETCH~unique, VGPR 64, no spill)
// with two surgical reductions:
//  1) double-buffered LDS prefix arrays -> ONE lgkm-barrier per iteration
//     (was 2). Safe: HWIN reads of buf A at iter i precede the barrier at
//     iter i+1 (program order); HSTORE writes to A at iter i+2 follow it.
//  2) 4-array fusion (SSIM only needs Sxx+Syy): 5 arrays -> 4, cutting
//     HSTORE/HWIN LDS traffic and prefix VALU by 20%.
// R1-R4 evidence: shuffle/8-col rewrite loses to register pressure (spills
// or 1.5-wave occupancy); split parity blocks double FETCH (L1 sharing
// between the two groups is what keeps FETCH at unique). So both parity
// groups stay in ONE 256-thread block, loads byte-identical to R0.
// ---------------------------------------------------------------------------

// LDS-only barrier (block_sync_lds): waits lgkmcnt(0) but NOT vmcnt ->
// prefetched global loads stay in flight across barriers.
// 0xC07F = vmcnt 63 (no wait), expcnt 7 (no wait), lgkmcnt 0 (wait all).
__device__ __forceinline__ void sync_lds() {
  __builtin_amdgcn_s_waitcnt(0xC07F);
  __builtin_amdgcn_s_barrier();
}

// SSIM on raw [0,1) values (scale-invariant: C1,C2 divided by 255^2),
// numerator/denominator premultiplied by NP^2 (NP=49). sss = Wxx+Wyy.
__device__ __forceinline__ float ssim_fast(float a, float b, float sss,
                                           float sxy) {
  const float K1 = 0.2401f;        // 2401 * 1e-4
  const float K2 = 2.1609f;        // 2401 * 9e-4
  const float cA = 49.0f / 24.0f;
  const float cB = 49.0f / 48.0f;
  float ab = a * b;
  float s2 = fmaf(a, a, b * b);
  float A1 = fmaf(2.0f, ab, K1);
  float B1 = s2 + K1;
  float A2 = fmaf(cA, fmaf(49.0f, sxy, -ab), K2);
  float B2 = fmaf(cB, fmaf(49.0f, sss, -s2), K2);
  return (A1 * A2) * __builtin_amdgcn_rcpf(B1 * B2);
}

// prefix within the thread's 4 columns, store (P0,P1) / (P2,P3) to LDS buf L
#define HSTORE(S, P, A)                          \
  P.x = S.x; P.y = P.x + S.y;                    \
  P.z = P.y + S.z; P.w = P.z + S.w;              \
  L[A][0][q] = make_float2(P.x, P.y);            \
  L[A][1][q] = make_float2(P.z, P.w);

// 7-wide windows at cols 4q..4q+3 from own prefixes + neighbor prefixes
#define HWIN(P, W, A) {                          \
  float2 h1 = L[A][1][q + 1];                    \
  float2 l2 = L[A][0][q + 2];                    \
  W.x = P.w + h1.x;                              \
  W.y = (P.w - P.x) + h1.y;                      \
  W.z = (P.w - P.y) + (h1.y + l2.x);             \
  W.w = (P.w - P.z) + (h1.y + l2.y); }

#define LREC(xv, yv) {                                         \
  float4 d_ = make_float4(xv.x - yv.x, xv.y - yv.y,            \
                          xv.z - yv.z, xv.w - yv.w);           \
  sabs += fabsf(d_.x) + fabsf(d_.y) + fabsf(d_.z) + fabsf(d_.w); \
  ssq += d_.x * d_.x + d_.y * d_.y;                            \
  ssq += d_.z * d_.z + d_.w * d_.w; }

#define VADD(xv, yv)                                    \
  Sx += xv; Sy += yv;                                   \
  Ss += xv * xv + yv * yv; Sp += xv * yv;

#define VSUB(xv, yv)                                    \
  Sx -= xv; Sy -= yv;                                   \
  Ss -= xv * xv + yv * yv; Sp -= xv * yv;

// grid (STRIPS, FRAMES), block 256 = two 128-thread parity groups.
// Group 0 (waves 0-1): even relative output rows; group 1: odd rows.
// Thread q in a group owns cols 4q..4q+3. Strip s covers output rows
// [32s, 32s+n_out), n_out = 32 (s<15) or 26 (s=15); owns input rows
// [32s, 32s+32) for L_rec (grp0 counts rel<=30 on first touch, grp1
// counts rel==31).
__global__ __launch_bounds__(256, 4) void fused_kernel(
    const float* __restrict__ gsrc, const float* __restrict__ tsrc,
    float* __restrict__ ws) {
  const int strip = blockIdx.x;
  const int frame = blockIdx.y;
  const int row0 = strip * 32;
  const int n_iter = (strip == STRIPS - 1) ? 13 : 16;  // output-row pairs
  const int tid = threadIdx.x;
  const int grp = tid >> 7;
  const int q = tid & 127;

  const float* gp = gsrc + ((size_t)frame * HH + row0 + grp) * WW + q * 4;
  const float* tp = tsrc + ((size_t)frame * HH + row0 + grp) * WW + q * 4;

  // [group][buffer][array][lo/hi][q(+pad)] = 33.8 KB
  __shared__ float2 lds[2][2][4][2][132];

  float4 Sx = make_float4(0.f, 0.f, 0.f, 0.f);
  float4 Sy = Sx, Ss = Sx, Sp = Sx;
  float sabs = 0.f, ssq = 0.f, ssum = 0.f;

  // init window: rel rows grp..grp+6 (grp0's rows 0..6 are all owned)
  for (int i = 0; i < 7; ++i) {
    float4 xv = *(const float4*)(gp + i * WW);
    float4 yv = *(const float4*)(tp + i * WW);
    VADD(xv, yv)
    if (grp == 0) { LREC(xv, yv) }
  }

  for (int it = 0; it < n_iter; ++it) {
    const bool slide = (it + 1 < n_iter);
    // ---- prefetch the slide rows NOW; consume after the barrier ----
    float4 nx0, ny0, nx1, ny1, ox0, oy0, ox1, oy1;
    if (slide) {
      const float* pn = gp + (size_t)(2 * it + 7) * WW;
      const float* qn = tp + (size_t)(2 * it + 7) * WW;
      const float* po = gp + (size_t)(2 * it) * WW;
      const float* qo = tp + (size_t)(2 * it) * WW;
      nx0 = *(const float4*)pn;
      ny0 = *(const float4*)qn;
      nx1 = *(const float4*)(pn + WW);
      ny1 = *(const float4*)(qn + WW);
      ox0 = *(const float4*)po;
      oy0 = *(const float4*)qo;
      ox1 = *(const float4*)(po + WW);
      oy1 = *(const float4*)(qo + WW);
    }

    // double-buffer: write/read buffer (it&1); safe with ONE barrier/iter
    float2 (&L)[4][2][132] = lds[grp][it & 1];

    float4 Px, Py, Ps, Pp;
    HSTORE(Sx, Px, 0) HSTORE(Sy, Py, 1) HSTORE(Ss, Ps, 2) HSTORE(Sp, Pp, 3)
    sync_lds();  // lgkm-only: prefetched vm loads stay in flight
    float4 Wx, Wy, Wss, Wxy;
    HWIN(Px, Wx, 0) HWIN(Py, Wy, 1) HWIN(Ps, Wss, 2) HWIN(Pp, Wxy, 3)
    float v0 = ssim_fast(Wx.x, Wy.x, Wss.x, Wxy.x);
    float v1 = ssim_fast(Wx.y, Wy.y, Wss.y, Wxy.y);
    float v2 = ssim_fast(Wx.z, Wy.z, Wss.z, Wxy.z);
    float v3 = ssim_fast(Wx.w, Wy.w, Wss.w, Wxy.w);
    // valid output cols: 4q+j <= 505 (506 outputs); select-then-add is
    // NaN-safe against garbage in the LDS pad region.
    ssum += (q <= 126) ? v0 : 0.f;
    ssum += (q <= 126) ? v1 : 0.f;
    ssum += (q <= 125) ? v2 : 0.f;
    ssum += (q <= 125) ? v3 : 0.f;
    // no second barrier: next iteration writes the OTHER buffer; writes to
    // THIS buffer (iter it+2) are fenced by iteration it+1's barrier.

    if (slide) {
      // consume prefetched rows: add rel (2it+7,2it+8)+grp, retire
      // (2it,2it+1)+grp. Retired rows re-read from global: exact same
      // values as when added -> exact cancellation.
      VADD(nx0, ny0)
      VSUB(ox0, oy0)
      if ((grp == 0) && (2 * it + 7 <= 30)) { LREC(nx0, ny0) }
      VADD(nx1, ny1)
      VSUB(ox1, oy1)
      bool cnt = (grp == 0) ? (2 * it + 8 <= 30) : (2 * it + 9 == 31);
      if (cnt) { LREC(nx1, ny1) }
    }
  }

  // block reduce sabs / ssq / ssum
  #pragma unroll
  for (int off = 32; off > 0; off >>= 1) {
    sabs += __shfl_down(sabs, off, 64);
    ssq += __shfl_down(ssq, off, 64);
    ssum += __shfl_down(ssum, off, 64);
  }
  __syncthreads();  // full barrier before reusing lds as scratch
  float* scr = (float*)&lds[0][0][0][0][0];
  const int lane = tid & 63, wv = tid >> 6;
  if (lane == 0) { scr[wv] = sabs; scr[4 + wv] = ssq; scr[8 + wv] = ssum; }
  __syncthreads();
  if (tid == 0) {
    const int bid = blockIdx.y * STRIPS + blockIdx.x;
    ws[bid] = scr[0] + scr[1] + scr[2] + scr[3];
    ws[NBLK + bid] = scr[4] + scr[5] + scr[6] + scr[7];
    ws[2 * NBLK + bid] = scr[8] + scr[9] + scr[10] + scr[11];
  }
}

__global__ __launch_bounds__(256) void finalize_kernel(
    const float* __restrict__ ws, const float* __restrict__ genD,
    float* __restrict__ out) {
  const int tid = threadIdx.x;
  float a = 0.f, b = 0.f, c = 0.f;
  for (int i = tid; i < NBLK; i += 256) {
    a += ws[i];
    b += ws[NBLK + i];
    c += ws[2 * NBLK + i];
  }
  #pragma unroll
  for (int off = 32; off > 0; off >>= 1) {
    a += __shfl_down(a, off, 64);
    b += __shfl_down(b, off, 64);
    c += __shfl_down(c, off, 64);
  }
  __shared__ float la[4], lb[4], lc[4];
  const int lane = tid & 63, wv = tid >> 6;
  if (lane == 0) { la[wv] = a; lb[wv] = b; lc[wv] = c; }
  __syncthreads();
  if (tid == 0) {
    a = la[0] + la[1] + la[2] + la[3];
    b = lb[0] + lb[1] + lb[2] + lb[3];
    c = lc[0] + lc[1] + lc[2] + lc[3];
    const float invN = 1.0f / (float)NTOT;
    float L_rec = a * invN + b * invN;
    float L_ssim = c / (160.0f * 506.0f * 506.0f);
    float d = 0.f;
    #pragma unroll
    for (int i = 0; i < 8; ++i) d += genD[i];
    float L_adv = -d / 8.0f;
    float L_total = L_rec + 0.01f * (1.0f - L_ssim) + 0.0001f * L_adv;
    out[0] = L_total;
    out[1] = L_rec;
    out[2] = L_ssim;
    out[3] = L_adv;
  }
}

extern "C" void kernel_launch(void* const* d_in, const int* in_sizes, int n_in,
                              void* d_out, int out_size, void* d_ws,
                              size_t ws_size, hipStream_t stream) {
  const float* gen_img = (const float*)d_in[0];
  const float* target = (const float*)d_in[1];
  const float* gen_D = (const float*)d_in[2];
  float* out = (float*)d_out;
  float* ws = (float*)d_ws;

  dim3 grid(STRIPS, FRAMES);
  fused_kernel<<<grid, 256, 0, stream>>>(gen_img, target, ws);
  finalize_kernel<<<1, 256, 0, stream>>>(ws, gen_D, out);
}